// Round 9
// baseline (164.736 us; speedup 1.0000x reference)
//
#include <hip/hip_runtime.h>

typedef __attribute__((ext_vector_type(8))) short short8;
typedef __attribute__((ext_vector_type(4))) float f32x4;
typedef __attribute__((ext_vector_type(4))) unsigned int u32x4;

#define C_TOT 256
#define O_TOT 256
#define HW_   784
#define NT_   128
#define KMAX  1792
#define XBYTES (NT_ * C_TOT * HW_ * 4)   // 102,760,448 bytes of x
#define MARKER 0x60000000u               // invalid-tap offset: OOB for buffer bounds-check

// ws layout (bytes):
//   meta  u32[4]          @ 0
//   idx   u32[KMAX]       @ WS_IDX_OFF     (c | dtm<<8)
//   cval  f32[KMAX]       @ WS_CVAL_OFF
//   offt  u32[8][KMAX]    @ WS_OFFT_OFF    per-t byte offsets (or MARKER)
//   A2    bf16[256*Kpad]  @ WS_A2_OFF
#define WS_IDX_OFF  16
#define WS_CVAL_OFF (WS_IDX_OFF + 4 * KMAX)
#define WS_OFFT_OFF (WS_CVAL_OFF + 4 * KMAX)
#define WS_A2_OFF   (WS_OFFT_OFF + 4 * 8 * KMAX)

#if __has_builtin(__builtin_amdgcn_make_buffer_rsrc) && __has_builtin(__builtin_amdgcn_raw_buffer_load_b32)
#define USE_RAW_BUF 1
#else
#define USE_RAW_BUF 0
#endif

__device__ __forceinline__ unsigned short f2b(float f) {
    union { float f; unsigned int u; } cv; cv.f = f;
    unsigned int u = cv.u;
    u += 0x7fffu + ((u >> 16) & 1u);   // round-to-nearest-even
    return (unsigned short)(u >> 16);
}

// ---- pre-pass 1: tap enumeration + per-t offset tables ----
__global__ __launch_bounds__(256)
void build_idx(const float* __restrict__ w3, const float* __restrict__ w5,
               const float* __restrict__ w7, unsigned int* __restrict__ meta,
               unsigned int* __restrict__ idx, float* __restrict__ cval,
               unsigned int* __restrict__ offt)
{
    const int c = threadIdx.x;

    float cf[7];
    #pragma unroll
    for (int i = 0; i < 7; ++i) cf[i] = 0.f;
    if (c < 128) {
        #pragma unroll
        for (int i = 0; i < 3; ++i) cf[i + 2] = w3[c * 3 + i];
    } else if (c < 192) {
        #pragma unroll
        for (int i = 0; i < 5; ++i) cf[i + 1] = w5[(c - 128) * 5 + i];
    } else {
        #pragma unroll
        for (int i = 0; i < 7; ++i) cf[i] = w7[(c - 192) * 7 + i];
    }
    int cnt = 0;
    #pragma unroll
    for (int i = 0; i < 7; ++i) cnt += (cf[i] != 0.f);

    __shared__ int sc[256];
    sc[c] = cnt;
    __syncthreads();
    for (int off = 1; off < 256; off <<= 1) {   // inclusive scan
        int u = 0;
        if (c >= off) u = sc[c - off];
        __syncthreads();
        sc[c] += u;
        __syncthreads();
    }
    const int start = sc[c] - cnt;
    int J = sc[255];
    if (J > KMAX) J = KMAX;
    int Kpad = (J + 31) & ~31;
    if (Kpad > KMAX) Kpad = KMAX;
    if (c == 0) { meta[0] = (unsigned int)Kpad; meta[1] = (unsigned int)J; }

    int j = start;
    #pragma unroll
    for (int i = 0; i < 7; ++i) {
        if (cf[i] != 0.f) {
            if (j < KMAX) {
                idx[j] = (unsigned int)c | ((unsigned int)i << 8);
                cval[j] = cf[i];
                const int dt  = i - 3;
                const int lin = (dt * C_TOT + c) * (HW_ * 4);  // byte offset (may be <0)
                #pragma unroll
                for (int tt = 0; tt < 8; ++tt) {
                    const int tf = tt + dt;
                    offt[tt * KMAX + j] =
                        (tf >= 0 && tf < 8) ? (unsigned int)lin : MARKER;
                }
            }
            ++j;
        }
    }
    for (int p = J + c; p < Kpad; p += 256) {    // pad entries: never read x
        idx[p] = 3u << 8;
        cval[p] = 0.f;
        #pragma unroll
        for (int tt = 0; tt < 8; ++tt) offt[tt * KMAX + p] = MARKER;
    }
}

// ---- pre-pass 2: A2[o][j] = net_w[o][c_j] * cval[j], bf16 ----
__global__ __launch_bounds__(256)
void build_A2(const float* __restrict__ netw, const unsigned int* __restrict__ meta,
              const unsigned int* __restrict__ idx, const float* __restrict__ cval,
              unsigned short* __restrict__ A2)
{
    const int o = blockIdx.x;
    const int Kpad = (int)meta[0];
    for (int j = threadIdx.x; j < Kpad; j += 256) {
        const int c = (int)(idx[j] & 255u);
        A2[(size_t)o * Kpad + j] = f2b(netw[o * C_TOT + c] * cval[j]);
    }
}

// ---- streaming full-M gather GEMM ----
// Each WAVE independently computes a 256(o) x 16(px) strip of one frame:
// acc = 16 m-frags, B-frag = 8 bounds-checked dword gathers per K-step,
// explicit depth-2 pipeline, no LDS, no barriers, no shuffles.
// XCD swizzle maps 16 consecutive frames to each XCD -> tap reuse hits L2.
__global__ __launch_bounds__(256, 2)
void msce_stream(const float* __restrict__ x,
                 const unsigned short* __restrict__ A2,
                 const unsigned int* __restrict__ offt,
                 const unsigned int* __restrict__ meta,
                 const float* __restrict__ net_b,
                 float* __restrict__ out)
{
    const int Kpad = (int)meta[0];
    const int KK   = Kpad >> 5;

    const int tid  = threadIdx.x;
    const int wave = tid >> 6;
    const int lane = tid & 63;

#if USE_RAW_BUF
    const __amdgpu_buffer_rsrc_t rsrc =
        __builtin_amdgcn_make_buffer_rsrc((void*)x, (short)0,
                                          (int)XBYTES, 0x00020000);
    #define GLOAD(ofs) __builtin_bit_cast(float, \
        __builtin_amdgcn_raw_buffer_load_b32(rsrc, (int)(ofs), 0, 0))
#else
    #define GLOAD(ofs) (((ofs) < (unsigned int)XBYTES) ? x[(ofs) >> 2] : 0.f)
#endif

    // XCD-locality swizzle: 1568 blocks = 8 XCDs x 196
    const int bid  = blockIdx.x;
    const int work = (bid & 7) * 196 + (bid >> 3);
    const int s    = work * 4 + wave;        // strip 0..6271
    const int n    = s / 49;                 // frame 0..127
    const int px0  = (s - n * 49) * 16;      // 784 = 49*16, exact
    const int t    = n & 7;

    const unsigned int n_off = (unsigned int)n * (unsigned int)(C_TOT * HW_ * 4);
    const unsigned int pcol4 = (unsigned int)((px0 + (lane & 15)) * 4);
    const int koct = lane >> 4;
    const int kg   = lane >> 4;
    const int arow = lane & 15;
    const unsigned int* offrow = offt + (size_t)t * KMAX;

    // acc init = bias (D layout: col=lane&15=px, row=ms*16+kg*4+r)
    f32x4 acc[16];
    #pragma unroll
    for (int ms = 0; ms < 16; ++ms)
        acc[ms] = *reinterpret_cast<const f32x4*>(&net_b[ms * 16 + kg * 4]);

    if (KK == 11) {   // Kpad == 352 for this weight pattern
        unsigned int off_[2][8];
        float        g_[2][8];
        #pragma unroll
        for (int e = 0; e < 8; ++e) off_[0][e] = offrow[koct * 8 + e];
        #pragma unroll
        for (int e = 0; e < 8; ++e) off_[1][e] = offrow[32 + koct * 8 + e];
        #pragma unroll
        for (int e = 0; e < 8; ++e)
            g_[0][e] = GLOAD(n_off + off_[0][e] + pcol4);

        #pragma unroll
        for (int kk = 0; kk < 11; ++kk) {
            const int cur = kk & 1, nxt = cur ^ 1;
            // gathers for kk+1 (offsets ready from two steps ago)
            if (kk + 1 < 11) {
                #pragma unroll
                for (int e = 0; e < 8; ++e)
                    g_[nxt][e] = GLOAD(n_off + off_[nxt][e] + pcol4);
            }
            // offsets for kk+2 (L2-hot table)
            if (kk + 2 < 11) {
                #pragma unroll
                for (int e = 0; e < 8; ++e)
                    off_[cur][e] = offrow[(kk + 2) * 32 + koct * 8 + e];
            }
            // A-fragments for kk (A2 L2-resident; static addresses, hoistable)
            short8 af[16];
            const int acol = kk * 32 + koct * 8;
            #pragma unroll
            for (int ms = 0; ms < 16; ++ms)
                af[ms] = *reinterpret_cast<const short8*>(
                             &A2[(size_t)(ms * 16 + arow) * Kpad + acol]);
            // pack current B-frag to bf16
            u32x4 bw;
            bw[0] = (unsigned int)f2b(g_[cur][0]) | ((unsigned int)f2b(g_[cur][1]) << 16);
            bw[1] = (unsigned int)f2b(g_[cur][2]) | ((unsigned int)f2b(g_[cur][3]) << 16);
            bw[2] = (unsigned int)f2b(g_[cur][4]) | ((unsigned int)f2b(g_[cur][5]) << 16);
            bw[3] = (unsigned int)f2b(g_[cur][6]) | ((unsigned int)f2b(g_[cur][7]) << 16);
            const short8 bfr = __builtin_bit_cast(short8, bw);
            #pragma unroll
            for (int ms = 0; ms < 16; ++ms)
                acc[ms] = __builtin_amdgcn_mfma_f32_16x16x32_bf16(
                              af[ms], bfr, acc[ms], 0, 0, 0);
        }
    } else {          // generic fallback (unpipelined)
        for (int kk = 0; kk < KK; ++kk) {
            float g[8];
            #pragma unroll
            for (int e = 0; e < 8; ++e) {
                const unsigned int off = offrow[kk * 32 + koct * 8 + e];
                g[e] = GLOAD(n_off + off + pcol4);
            }
            short8 af[16];
            const int acol = kk * 32 + koct * 8;
            #pragma unroll
            for (int ms = 0; ms < 16; ++ms)
                af[ms] = *reinterpret_cast<const short8*>(
                             &A2[(size_t)(ms * 16 + arow) * Kpad + acol]);
            u32x4 bw;
            bw[0] = (unsigned int)f2b(g[0]) | ((unsigned int)f2b(g[1]) << 16);
            bw[1] = (unsigned int)f2b(g[2]) | ((unsigned int)f2b(g[3]) << 16);
            bw[2] = (unsigned int)f2b(g[4]) | ((unsigned int)f2b(g[5]) << 16);
            bw[3] = (unsigned int)f2b(g[6]) | ((unsigned int)f2b(g[7]) << 16);
            const short8 bfr = __builtin_bit_cast(short8, bw);
            #pragma unroll
            for (int ms = 0; ms < 16; ++ms)
                acc[ms] = __builtin_amdgcn_mfma_f32_16x16x32_bf16(
                              af[ms], bfr, acc[ms], 0, 0, 0);
        }
    }
    #undef GLOAD

    // ---- store: out[n][o][px], f32 (16 lanes -> 64B lines, 4 rows/instr) ----
    const size_t outbase = ((size_t)n * O_TOT) * HW_ + (size_t)(px0 + (lane & 15));
    #pragma unroll
    for (int ms = 0; ms < 16; ++ms) {
        #pragma unroll
        for (int r = 0; r < 4; ++r) {
            const int o = ms * 16 + kg * 4 + r;
            out[outbase + (size_t)o * HW_] = acc[ms][r];
        }
    }
}

extern "C" void kernel_launch(void* const* d_in, const int* in_sizes, int n_in,
                              void* d_out, int out_size, void* d_ws, size_t ws_size,
                              hipStream_t stream) {
    const float* x    = (const float*)d_in[0];
    const float* w3p  = (const float*)d_in[1];
    const float* w5p  = (const float*)d_in[2];
    const float* w7p  = (const float*)d_in[3];
    const float* netw = (const float*)d_in[4];
    const float* netb = (const float*)d_in[5];
    float* outp = (float*)d_out;

    char* ws = (char*)d_ws;
    unsigned int*   meta  = (unsigned int*)ws;
    unsigned int*   idx   = (unsigned int*)(ws + WS_IDX_OFF);
    float*          cval  = (float*)(ws + WS_CVAL_OFF);
    unsigned int*   offt  = (unsigned int*)(ws + WS_OFFT_OFF);
    unsigned short* A2    = (unsigned short*)(ws + WS_A2_OFF);

    hipLaunchKernelGGL(build_idx, dim3(1), dim3(256), 0, stream,
                       w3p, w5p, w7p, meta, idx, cval, offt);
    hipLaunchKernelGGL(build_A2, dim3(256), dim3(256), 0, stream,
                       netw, meta, idx, cval, A2);

    hipLaunchKernelGGL(msce_stream, dim3(1568), dim3(256), 0, stream,
                       x, A2, offt, meta, netb, outp);
}

// Round 11
// 82.199 us; speedup vs baseline: 2.0041x; 2.0041x over previous
//
#include <hip/hip_runtime.h>
#include <hip/hip_bf16.h>

typedef __attribute__((ext_vector_type(8))) short short8;
typedef __attribute__((ext_vector_type(4))) float f32x4;
typedef __attribute__((ext_vector_type(4))) unsigned int u32x4;

#define C_TOT 256
#define O_TOT 256
#define HW_   784
#define KMAX  1792
#define KPAD_STD 352          // Kpad for this weight pattern (fast path)

// ws layout (bytes):
//   meta  u32[4]            @ 0
//   idx   u32[KMAX]         @ WS_IDX_OFF   (c | dtm<<8)
//   cval  f32[KMAX]         @ WS_CVAL_OFF
//   A3    bf16[(KMAX/8)*256*8] @ WS_A3_OFF  per-lane fragment order:
//         A3[(slot*256 + o)*8 + e], slot = kk*4+koct, c-index = slot*8+e
#define WS_IDX_OFF  16
#define WS_CVAL_OFF (WS_IDX_OFF + 4 * KMAX)
#define WS_A3_OFF   (WS_CVAL_OFF + 4 * KMAX)

__device__ __forceinline__ unsigned int pk2(float lo, float hi) {
    float2 f; f.x = lo; f.y = hi;
    __hip_bfloat162 h = __float22bfloat162_rn(f);   // v_cvt_pk_bf16_f32
    unsigned int r;
    __builtin_memcpy(&r, &h, 4);
    return r;
}
__device__ __forceinline__ unsigned short f2b(float f) {
    union { float f; unsigned int u; } cv; cv.f = f;
    unsigned int u = cv.u;
    u += 0x7fffu + ((u >> 16) & 1u);
    return (unsigned short)(u >> 16);
}

// ---- pre-pass 1: enumerate nonzero taps (c,dt) in (c,dt) order ----
__global__ __launch_bounds__(256)
void build_idx(const float* __restrict__ w3, const float* __restrict__ w5,
               const float* __restrict__ w7, unsigned int* __restrict__ meta,
               unsigned int* __restrict__ idx, float* __restrict__ cval)
{
    const int c = threadIdx.x;
    float cf[7];
    #pragma unroll
    for (int i = 0; i < 7; ++i) cf[i] = 0.f;
    if (c < 128) {
        #pragma unroll
        for (int i = 0; i < 3; ++i) cf[i + 2] = w3[c * 3 + i];
    } else if (c < 192) {
        #pragma unroll
        for (int i = 0; i < 5; ++i) cf[i + 1] = w5[(c - 128) * 5 + i];
    } else {
        #pragma unroll
        for (int i = 0; i < 7; ++i) cf[i] = w7[(c - 192) * 7 + i];
    }
    int cnt = 0;
    #pragma unroll
    for (int i = 0; i < 7; ++i) cnt += (cf[i] != 0.f);

    __shared__ int sc[256];
    sc[c] = cnt;
    __syncthreads();
    for (int off = 1; off < 256; off <<= 1) {
        int u = 0;
        if (c >= off) u = sc[c - off];
        __syncthreads();
        sc[c] += u;
        __syncthreads();
    }
    const int start = sc[c] - cnt;
    int J = sc[255];
    if (J > KMAX) J = KMAX;
    int Kpad = (J + 31) & ~31;
    if (Kpad > KMAX) Kpad = KMAX;
    if (c == 0) { meta[0] = (unsigned int)Kpad; meta[1] = (unsigned int)J; }

    int j = start;
    #pragma unroll
    for (int i = 0; i < 7; ++i) {
        if (cf[i] != 0.f) {
            if (j < KMAX) { idx[j] = (unsigned int)c | ((unsigned int)i << 8); cval[j] = cf[i]; }
            ++j;
        }
    }
    for (int p = J + c; p < Kpad; p += 256) {
        idx[p] = 3u << 8;     // dt=0, c=0, coef=0
        cval[p] = 0.f;
    }
}

// ---- pre-pass 2: A3 in per-lane MFMA fragment order ----
// A3[(slot*256 + o)*8 + e] = net_w[o][c_{slot*8+e}] * cval[slot*8+e]
__global__ __launch_bounds__(256)
void build_A3(const float* __restrict__ netw, const unsigned int* __restrict__ meta,
              const unsigned int* __restrict__ idx, const float* __restrict__ cval,
              unsigned short* __restrict__ A3)
{
    const int o = blockIdx.x;
    const int Kpad   = (int)meta[0];
    const int nslots = Kpad >> 3;
    for (int s = threadIdx.x; s < nslots; s += 256) {
        unsigned short v[8];
        #pragma unroll
        for (int e = 0; e < 8; ++e) {
            const int jj = s * 8 + e;
            const int c  = (int)(idx[jj] & 255u);
            v[e] = f2b(netw[o * C_TOT + c] * cval[jj]);
        }
        *reinterpret_cast<u32x4*>(&A3[((size_t)s * 256 + o) * 8]) =
            *reinterpret_cast<const u32x4*>(v);
    }
}

// ---- fused gathered-K GEMM (round-4 structure, leaner) ----
// Block: one frame n x one 64-pixel tile. 4 waves, each 64(o) x 64(p).
// Register-staged B, double-buffered LDS, one __syncthreads per K-step,
// depth-2 register prefetch, fully unrolled KK=11 fast path.
__global__ __launch_bounds__(256, 4)
void msce_fused(const float* __restrict__ x,
                const unsigned short* __restrict__ A3,
                const unsigned int* __restrict__ gidx,
                const unsigned int* __restrict__ meta,
                const float* __restrict__ net_b,
                float* __restrict__ out)
{
    __shared__ unsigned int s_idx[KPAD_STD];
    __shared__ __align__(16) unsigned int Bl[2][64 * 20];  // 2 x (64 rows x 80B)

    const int tid  = threadIdx.x;
    const int wave = tid >> 6;
    const int lane = tid & 63;
    const int tile = blockIdx.x;
    const int n    = blockIdx.y;
    const int p0   = tile * 64;
    const int t    = n & 7;

    const int Kpad = (int)meta[0];
    const int KK   = Kpad >> 5;
    const bool fast = (Kpad == KPAD_STD);

    if (fast)
        for (int i = tid; i < KPAD_STD; i += 256) s_idx[i] = gidx[i];

    // acc init = bias (D layout: col=lane&15, row=(lane>>4)*4+r)
    f32x4 acc[4][4];
    {
        const int r0 = wave * 64 + (lane >> 4) * 4;
        #pragma unroll
        for (int ms = 0; ms < 4; ++ms) {
            float b[4];
            #pragma unroll
            for (int r = 0; r < 4; ++r) b[r] = net_b[r0 + ms * 16 + r];
            #pragma unroll
            for (int ns = 0; ns < 4; ++ns)
                #pragma unroll
                for (int r = 0; r < 4; ++r) acc[ms][ns][r] = b[r];
        }
    }

    const int cq = lane & 7;
    const int pq = lane >> 3;
    const int pb = p0 + pq * 8;
    const bool pvalid = pb < HW_;
    const int koct = lane >> 4;
    const int orow = wave * 64 + (lane & 15);

    __syncthreads();   // s_idx ready

    auto issue_x = [&](int kk, f32x4& u0, f32x4& u1) {
        const unsigned int e = fast ? s_idx[kk * 32 + wave * 8 + cq]
                                    : gidx[kk * 32 + wave * 8 + cq];
        const int c   = (int)(e & 255u);
        const int dtm = (int)((e >> 8) & 7u);
        const int tt  = t + dtm - 3;
        const bool v  = pvalid && (tt >= 0) && (tt < 8);
        u0 = (f32x4)0.f; u1 = (f32x4)0.f;
        if (v) {
            const float* src = x + ((size_t)(n + dtm - 3) * C_TOT + c) * HW_ + pb;
            u0 = *reinterpret_cast<const f32x4*>(src);
            u1 = *reinterpret_cast<const f32x4*>(src + 4);
        }
    };

    auto step = [&](int kk, int KKr, f32x4& cu0, f32x4& cu1,
                    f32x4& nu0, f32x4& nu1, f32x4& nn0, f32x4& nn1) {
        if (kk + 2 < KKr) issue_x(kk + 2, nn0, nn1);
        else { nn0 = (f32x4)0.f; nn1 = (f32x4)0.f; }

        unsigned int v0 = pk2(cu0[0], cu0[1]);
        unsigned int v1 = pk2(cu0[2], cu0[3]);
        unsigned int v2 = pk2(cu1[0], cu1[1]);
        unsigned int v3 = pk2(cu1[2], cu1[3]);

        // 8x8 bf16 xor-butterfly transpose within 8-lane groups
        {
            unsigned int t0, t1, q0, q1;
            t0 = (cq & 4) ? v0 : v2;
            t1 = (cq & 4) ? v1 : v3;
            q0 = (unsigned int)__shfl_xor((int)t0, 4);
            q1 = (unsigned int)__shfl_xor((int)t1, 4);
            if (cq & 4) { v0 = q0; v1 = q1; } else { v2 = q0; v3 = q1; }
            t0 = (cq & 2) ? v0 : v1;
            t1 = (cq & 2) ? v2 : v3;
            q0 = (unsigned int)__shfl_xor((int)t0, 2);
            q1 = (unsigned int)__shfl_xor((int)t1, 2);
            if (cq & 2) { v0 = q0; v2 = q1; } else { v1 = q0; v3 = q1; }
            unsigned int s0 = (cq & 1) ? (v0 & 0xffffu) : (v0 >> 16);
            unsigned int s1 = (cq & 1) ? (v1 & 0xffffu) : (v1 >> 16);
            unsigned int s2 = (cq & 1) ? (v2 & 0xffffu) : (v2 >> 16);
            unsigned int s3 = (cq & 1) ? (v3 & 0xffffu) : (v3 >> 16);
            s0 = (unsigned int)__shfl_xor((int)s0, 1);
            s1 = (unsigned int)__shfl_xor((int)s1, 1);
            s2 = (unsigned int)__shfl_xor((int)s2, 1);
            s3 = (unsigned int)__shfl_xor((int)s3, 1);
            if (cq & 1) {
                v0 = (v0 & 0xffff0000u) | s0;
                v1 = (v1 & 0xffff0000u) | s1;
                v2 = (v2 & 0xffff0000u) | s2;
                v3 = (v3 & 0xffff0000u) | s3;
            } else {
                v0 = (v0 & 0xffffu) | (s0 << 16);
                v1 = (v1 & 0xffffu) | (s1 << 16);
                v2 = (v2 & 0xffffu) | (s2 << 16);
                v3 = (v3 & 0xffffu) | (s3 << 16);
            }
        }
        {
            u32x4 w4;
            w4[0] = v0; w4[1] = v1; w4[2] = v2; w4[3] = v3;
            *reinterpret_cast<u32x4*>(&Bl[kk & 1][lane * 20 + wave * 4]) = w4;
        }

        // A-fragments: per-lane fragment order, lanes 0..15 contiguous 256B
        short8 af[4];
        {
            const unsigned short* base = A3 + ((size_t)(kk * 4 + koct) * 256 + orow) * 8;
            #pragma unroll
            for (int ms = 0; ms < 4; ++ms)
                af[ms] = *reinterpret_cast<const short8*>(base + (size_t)ms * 16 * 8);
        }

        __syncthreads();   // B tile ready

        short8 bfr[4];
        #pragma unroll
        for (int ns = 0; ns < 4; ++ns) {
            u32x4 bw = *reinterpret_cast<const u32x4*>(
                           &Bl[kk & 1][(ns * 16 + (lane & 15)) * 20 + (lane >> 4) * 4]);
            bfr[ns] = __builtin_bit_cast(short8, bw);
        }
        #pragma unroll
        for (int ms = 0; ms < 4; ++ms)
            #pragma unroll
            for (int ns = 0; ns < 4; ++ns)
                acc[ms][ns] = __builtin_amdgcn_mfma_f32_16x16x32_bf16(
                                  af[ms], bfr[ns], acc[ms][ns], 0, 0, 0);

        cu0 = nu0; cu1 = nu1;
        nu0 = nn0; nu1 = nn1;
    };

    f32x4 cu0, cu1, nu0, nu1, nn0, nn1;
    issue_x(0, cu0, cu1);
    issue_x(1, nu0, nu1);   // KK >= 2 always (Kpad >= 64)

    if (fast) {
        #pragma unroll
        for (int kk = 0; kk < 11; ++kk)
            step(kk, 11, cu0, cu1, nu0, nu1, nn0, nn1);
    } else {
        for (int kk = 0; kk < KK; ++kk)
            step(kk, KK, cu0, cu1, nu0, nu1, nn0, nn1);
    }

    // ---- store: out[n][o][p], f32 ----
    const int prow = lane & 15;
    const int kg   = lane >> 4;
    #pragma unroll
    for (int ns = 0; ns < 4; ++ns) {
        const int p = p0 + ns * 16 + prow;
        if (p < HW_) {
            #pragma unroll
            for (int ms = 0; ms < 4; ++ms) {
                const int o = wave * 64 + ms * 16 + kg * 4;
                const size_t base = ((size_t)n * O_TOT + o) * HW_ + p;
                #pragma unroll
                for (int r = 0; r < 4; ++r)
                    out[base + (size_t)r * HW_] = acc[ms][ns][r];
            }
        }
    }
}

extern "C" void kernel_launch(void* const* d_in, const int* in_sizes, int n_in,
                              void* d_out, int out_size, void* d_ws, size_t ws_size,
                              hipStream_t stream) {
    const float* x    = (const float*)d_in[0];
    const float* w3p  = (const float*)d_in[1];
    const float* w5p  = (const float*)d_in[2];
    const float* w7p  = (const float*)d_in[3];
    const float* netw = (const float*)d_in[4];
    const float* netb = (const float*)d_in[5];
    float* outp = (float*)d_out;

    char* ws = (char*)d_ws;
    unsigned int*   meta = (unsigned int*)ws;
    unsigned int*   idx  = (unsigned int*)(ws + WS_IDX_OFF);
    float*          cval = (float*)(ws + WS_CVAL_OFF);
    unsigned short* A3   = (unsigned short*)(ws + WS_A3_OFF);

    hipLaunchKernelGGL(build_idx, dim3(1), dim3(256), 0, stream,
                       w3p, w5p, w7p, meta, idx, cval);
    hipLaunchKernelGGL(build_A3, dim3(256), dim3(256), 0, stream,
                       netw, meta, idx, cval, A3);

    dim3 grid(13, 128);
    hipLaunchKernelGGL(msce_fused, grid, dim3(256), 0, stream,
                       x, A3, idx, meta, netb, outp);
}

// Round 12
// 61.792 us; speedup vs baseline: 2.6660x; 1.3303x over previous
//
#include <hip/hip_runtime.h>
#include <hip/hip_bf16.h>

typedef __attribute__((ext_vector_type(8))) short short8;
typedef __attribute__((ext_vector_type(4))) float f32x4;
typedef __attribute__((ext_vector_type(4))) unsigned int u32x4;

#define C_TOT 256
#define O_TOT 256
#define HW_   784
#define NT_   128
#define KMAX  1792
#define KPAD_STD 352
#define XBYTES (NT_ * C_TOT * HW_ * 4)
#define MARKER 0x60000000u    // invalid-tap offset -> OOB for buffer bounds-check

// ws layout (bytes):
//   meta  u32[4]              @ 0
//   idx   u32[KMAX]           @ WS_IDX_OFF   (c | dtm<<8)
//   cval  f32[KMAX]           @ WS_CVAL_OFF
//   offt  u32[8][KMAX]        @ WS_OFFT_OFF  per-t relative byte offsets (or MARKER)
//   A3    bf16[(KMAX/8)*256*8]@ WS_A3_OFF    fragment-major: A3[(slot*256+o)*8+e]
#define WS_IDX_OFF  16
#define WS_CVAL_OFF (WS_IDX_OFF + 4 * KMAX)
#define WS_OFFT_OFF (WS_CVAL_OFF + 4 * KMAX)
#define WS_A3_OFF   (WS_OFFT_OFF + 4 * 8 * KMAX)

#if __has_builtin(__builtin_amdgcn_make_buffer_rsrc) && __has_builtin(__builtin_amdgcn_raw_buffer_load_b32)
#define USE_RAW_BUF 1
#else
#define USE_RAW_BUF 0
#endif

__device__ __forceinline__ unsigned int pk2(float lo, float hi) {
    float2 f; f.x = lo; f.y = hi;
    __hip_bfloat162 h = __float22bfloat162_rn(f);   // v_cvt_pk_bf16_f32
    unsigned int r;
    __builtin_memcpy(&r, &h, 4);
    return r;
}
__device__ __forceinline__ unsigned short f2b(float f) {
    union { float f; unsigned int u; } cv; cv.f = f;
    unsigned int u = cv.u;
    u += 0x7fffu + ((u >> 16) & 1u);
    return (unsigned short)(u >> 16);
}

// ---- pre-pass 1: tap enumeration + per-t offset tables ----
__global__ __launch_bounds__(256)
void build_idx(const float* __restrict__ w3, const float* __restrict__ w5,
               const float* __restrict__ w7, unsigned int* __restrict__ meta,
               unsigned int* __restrict__ idx, float* __restrict__ cval,
               unsigned int* __restrict__ offt)
{
    const int c = threadIdx.x;
    float cf[7];
    #pragma unroll
    for (int i = 0; i < 7; ++i) cf[i] = 0.f;
    if (c < 128) {
        #pragma unroll
        for (int i = 0; i < 3; ++i) cf[i + 2] = w3[c * 3 + i];
    } else if (c < 192) {
        #pragma unroll
        for (int i = 0; i < 5; ++i) cf[i + 1] = w5[(c - 128) * 5 + i];
    } else {
        #pragma unroll
        for (int i = 0; i < 7; ++i) cf[i] = w7[(c - 192) * 7 + i];
    }
    int cnt = 0;
    #pragma unroll
    for (int i = 0; i < 7; ++i) cnt += (cf[i] != 0.f);

    __shared__ int sc[256];
    sc[c] = cnt;
    __syncthreads();
    for (int off = 1; off < 256; off <<= 1) {
        int u = 0;
        if (c >= off) u = sc[c - off];
        __syncthreads();
        sc[c] += u;
        __syncthreads();
    }
    const int start = sc[c] - cnt;
    int J = sc[255];
    if (J > KMAX) J = KMAX;
    int Kpad = (J + 31) & ~31;
    if (Kpad > KMAX) Kpad = KMAX;
    if (c == 0) { meta[0] = (unsigned int)Kpad; meta[1] = (unsigned int)J; }

    int j = start;
    #pragma unroll
    for (int i = 0; i < 7; ++i) {
        if (cf[i] != 0.f) {
            if (j < KMAX) {
                idx[j] = (unsigned int)c | ((unsigned int)i << 8);
                cval[j] = cf[i];
                const int dt  = i - 3;
                const int lin = (dt * C_TOT + c) * (HW_ * 4);
                #pragma unroll
                for (int tt = 0; tt < 8; ++tt) {
                    const int tf = tt + dt;
                    offt[tt * KMAX + j] =
                        (tf >= 0 && tf < 8) ? (unsigned int)lin : MARKER;
                }
            }
            ++j;
        }
    }
    for (int p = J + c; p < Kpad; p += 256) {
        idx[p] = 3u << 8;
        cval[p] = 0.f;
        #pragma unroll
        for (int tt = 0; tt < 8; ++tt) offt[tt * KMAX + p] = MARKER;
    }
}

// ---- pre-pass 2: A3 fragment-major: A3[(slot*256+o)*8+e], slot=kk*4+koct ----
__global__ __launch_bounds__(256)
void build_A3(const float* __restrict__ netw, const unsigned int* __restrict__ meta,
              const unsigned int* __restrict__ idx, const float* __restrict__ cval,
              unsigned short* __restrict__ A3)
{
    const int o = blockIdx.x;
    const int Kpad   = (int)meta[0];
    const int nslots = Kpad >> 3;
    for (int s = threadIdx.x; s < nslots; s += 256) {
        unsigned short v[8];
        #pragma unroll
        for (int e = 0; e < 8; ++e) {
            const int jj = s * 8 + e;
            const int c  = (int)(idx[jj] & 255u);
            v[e] = f2b(netw[o * C_TOT + c] * cval[jj]);
        }
        *reinterpret_cast<u32x4*>(&A3[((size_t)s * 256 + o) * 8]) =
            *reinterpret_cast<const u32x4*>(v);
    }
}

// ---- barrier-free gather GEMM ----
// Block = one frame x one 64-px tile; wave = one 64-o group (fully independent:
// no LDS, no barriers, no shuffles). B-fragments built by direct bounds-checked
// dword gathers in MFMA layout; compiler pipelines across unrolled K-steps.
__global__ __launch_bounds__(256, 3)
void msce_gather(const float* __restrict__ x,
                 const unsigned short* __restrict__ A3,
                 const unsigned int* __restrict__ offt,
                 const unsigned int* __restrict__ meta,
                 const float* __restrict__ net_b,
                 float* __restrict__ out)
{
    const int Kpad = (int)meta[0];
    const int KK   = Kpad >> 5;

    const int tid  = threadIdx.x;
    const int wave = tid >> 6;       // = o-group 0..3
    const int lane = tid & 63;

#if USE_RAW_BUF
    const __amdgpu_buffer_rsrc_t rsrc =
        __builtin_amdgcn_make_buffer_rsrc((void*)x, (short)0,
                                          (int)XBYTES, 0x00020000);
    #define GLOAD(ofs) __builtin_bit_cast(float, \
        __builtin_amdgcn_raw_buffer_load_b32(rsrc, (int)(ofs), 0, 0))
#else
    #define GLOAD(ofs) (((ofs) < (unsigned int)XBYTES) ? x[(ofs) >> 2] : 0.f)
#endif

    // bijective XCD swizzle: 1664 = 8 x 208 -> 16 consecutive frames per XCD
    const int bid  = blockIdx.x;
    const int work = (bid & 7) * 208 + (bid >> 3);
    const int n    = work / 13;
    const int tile = work - n * 13;
    const int p0   = (tile < 12) ? tile * 64 : 720;   // tile 12 overlaps 11 (benign)
    const int t    = n & 7;

    const int og   = wave;
    const int koct = lane >> 4;
    const int prow = lane & 15;
    const unsigned int n_off = (unsigned int)n * (unsigned int)(C_TOT * HW_ * 4);
    const unsigned int* offrow = offt + (size_t)t * KMAX;

    // acc init = bias (D layout: col=prow, row = og*64 + ms*16 + koct*4 + r)
    f32x4 acc[4][4];
    #pragma unroll
    for (int ms = 0; ms < 4; ++ms) {
        const f32x4 b = *reinterpret_cast<const f32x4*>(
                            &net_b[og * 64 + ms * 16 + koct * 4]);
        #pragma unroll
        for (int ns = 0; ns < 4; ++ns) acc[ms][ns] = b;
    }

    auto step = [&](int kk) {
        // 8 relative row offsets for this lane's k-octet (L1/L2-hot table)
        unsigned int off8[8];
        #pragma unroll
        for (int e = 0; e < 8; ++e)
            off8[e] = offrow[kk * 32 + koct * 8 + e];

        // A-fragments: fragment-major, 16 lanes read 256B contiguous
        short8 af[4];
        const unsigned short* abase =
            A3 + ((size_t)(kk * 4 + koct) * 256 + og * 64 + prow) * 8;
        #pragma unroll
        for (int ms = 0; ms < 4; ++ms)
            af[ms] = *reinterpret_cast<const short8*>(abase + (size_t)ms * 16 * 8);

        // B-fragments: 8 gathers per ns, packed to bf16 pairs
        short8 bfr[4];
        #pragma unroll
        for (int ns = 0; ns < 4; ++ns) {
            const unsigned int pofs = n_off + (unsigned int)((p0 + ns * 16 + prow) * 4);
            float g[8];
            #pragma unroll
            for (int e = 0; e < 8; ++e)
                g[e] = GLOAD(off8[e] + pofs);
            u32x4 bw;
            bw[0] = pk2(g[0], g[1]);
            bw[1] = pk2(g[2], g[3]);
            bw[2] = pk2(g[4], g[5]);
            bw[3] = pk2(g[6], g[7]);
            bfr[ns] = __builtin_bit_cast(short8, bw);
        }

        #pragma unroll
        for (int ms = 0; ms < 4; ++ms)
            #pragma unroll
            for (int ns = 0; ns < 4; ++ns)
                acc[ms][ns] = __builtin_amdgcn_mfma_f32_16x16x32_bf16(
                                  af[ms], bfr[ns], acc[ms][ns], 0, 0, 0);
    };

    if (Kpad == KPAD_STD) {
        #pragma unroll
        for (int kk = 0; kk < 11; ++kk) step(kk);
    } else {
        for (int kk = 0; kk < KK; ++kk) step(kk);
    }
    #undef GLOAD

    // ---- store: out[n][o][p], f32 (identical to round-4 epilogue) ----
    #pragma unroll
    for (int ns = 0; ns < 4; ++ns) {
        const int p = p0 + ns * 16 + prow;
        #pragma unroll
        for (int ms = 0; ms < 4; ++ms) {
            const int o = og * 64 + ms * 16 + koct * 4;
            const size_t base = ((size_t)n * O_TOT + o) * HW_ + p;
            #pragma unroll
            for (int r = 0; r < 4; ++r)
                out[base + (size_t)r * HW_] = acc[ms][ns][r];
        }
    }
}

extern "C" void kernel_launch(void* const* d_in, const int* in_sizes, int n_in,
                              void* d_out, int out_size, void* d_ws, size_t ws_size,
                              hipStream_t stream) {
    const float* x    = (const float*)d_in[0];
    const float* w3p  = (const float*)d_in[1];
    const float* w5p  = (const float*)d_in[2];
    const float* w7p  = (const float*)d_in[3];
    const float* netw = (const float*)d_in[4];
    const float* netb = (const float*)d_in[5];
    float* outp = (float*)d_out;

    char* ws = (char*)d_ws;
    unsigned int*   meta = (unsigned int*)ws;
    unsigned int*   idx  = (unsigned int*)(ws + WS_IDX_OFF);
    float*          cval = (float*)(ws + WS_CVAL_OFF);
    unsigned int*   offt = (unsigned int*)(ws + WS_OFFT_OFF);
    unsigned short* A3   = (unsigned short*)(ws + WS_A3_OFF);

    hipLaunchKernelGGL(build_idx, dim3(1), dim3(256), 0, stream,
                       w3p, w5p, w7p, meta, idx, cval, offt);
    hipLaunchKernelGGL(build_A3, dim3(256), dim3(256), 0, stream,
                       netw, meta, idx, cval, A3);

    hipLaunchKernelGGL(msce_gather, dim3(1664), dim3(256), 0, stream,
                       x, A3, offt, meta, netb, outp);
}

// Round 13
// 61.068 us; speedup vs baseline: 2.6976x; 1.0119x over previous
//
#include <hip/hip_runtime.h>
#include <hip/hip_bf16.h>

typedef __attribute__((ext_vector_type(8))) short short8;
typedef __attribute__((ext_vector_type(4))) float f32x4;
typedef __attribute__((ext_vector_type(4))) unsigned int u32x4;

#define C_TOT 256
#define O_TOT 256
#define HW_   784
#define NT_   128
#define KMAX  1792
#define KPAD_STD 352
#define XBYTES (NT_ * C_TOT * HW_ * 4)
#define MARKER 0x60000000u    // invalid-tap offset -> OOB for buffer bounds-check

// ws layout (bytes):
//   meta  u32[4]              @ 0
//   idx   u32[KMAX]           @ WS_IDX_OFF   (c | dtm<<8)
//   cval  f32[KMAX]           @ WS_CVAL_OFF
//   offt  u32[8][KMAX]        @ WS_OFFT_OFF  per-t relative byte offsets (or MARKER)
//   A3    bf16[(KMAX/8)*256*8]@ WS_A3_OFF    fragment-major: A3[(slot*256+o)*8+e]
#define WS_IDX_OFF  16
#define WS_CVAL_OFF (WS_IDX_OFF + 4 * KMAX)
#define WS_OFFT_OFF (WS_CVAL_OFF + 4 * KMAX)
#define WS_A3_OFF   (WS_OFFT_OFF + 4 * 8 * KMAX)

#if __has_builtin(__builtin_amdgcn_make_buffer_rsrc) && __has_builtin(__builtin_amdgcn_raw_buffer_load_b32)
#define USE_RAW_BUF 1
#else
#define USE_RAW_BUF 0
#endif

__device__ __forceinline__ unsigned int pk2(float lo, float hi) {
    float2 f; f.x = lo; f.y = hi;
    __hip_bfloat162 h = __float22bfloat162_rn(f);   // v_cvt_pk_bf16_f32
    unsigned int r;
    __builtin_memcpy(&r, &h, 4);
    return r;
}
__device__ __forceinline__ unsigned short f2b(float f) {
    union { float f; unsigned int u; } cv; cv.f = f;
    unsigned int u = cv.u;
    u += 0x7fffu + ((u >> 16) & 1u);
    return (unsigned short)(u >> 16);
}

// ---- pre-pass 1: tap enumeration + per-t offset tables ----
__global__ __launch_bounds__(256)
void build_idx(const float* __restrict__ w3, const float* __restrict__ w5,
               const float* __restrict__ w7, unsigned int* __restrict__ meta,
               unsigned int* __restrict__ idx, float* __restrict__ cval,
               unsigned int* __restrict__ offt)
{
    const int c = threadIdx.x;
    float cf[7];
    #pragma unroll
    for (int i = 0; i < 7; ++i) cf[i] = 0.f;
    if (c < 128) {
        #pragma unroll
        for (int i = 0; i < 3; ++i) cf[i + 2] = w3[c * 3 + i];
    } else if (c < 192) {
        #pragma unroll
        for (int i = 0; i < 5; ++i) cf[i + 1] = w5[(c - 128) * 5 + i];
    } else {
        #pragma unroll
        for (int i = 0; i < 7; ++i) cf[i] = w7[(c - 192) * 7 + i];
    }
    int cnt = 0;
    #pragma unroll
    for (int i = 0; i < 7; ++i) cnt += (cf[i] != 0.f);

    __shared__ int sc[256];
    sc[c] = cnt;
    __syncthreads();
    for (int off = 1; off < 256; off <<= 1) {
        int u = 0;
        if (c >= off) u = sc[c - off];
        __syncthreads();
        sc[c] += u;
        __syncthreads();
    }
    const int start = sc[c] - cnt;
    int J = sc[255];
    if (J > KMAX) J = KMAX;
    int Kpad = (J + 31) & ~31;
    if (Kpad > KMAX) Kpad = KMAX;
    if (c == 0) { meta[0] = (unsigned int)Kpad; meta[1] = (unsigned int)J; }

    int j = start;
    #pragma unroll
    for (int i = 0; i < 7; ++i) {
        if (cf[i] != 0.f) {
            if (j < KMAX) {
                idx[j] = (unsigned int)c | ((unsigned int)i << 8);
                cval[j] = cf[i];
                const int dt  = i - 3;
                const int lin = (dt * C_TOT + c) * (HW_ * 4);
                #pragma unroll
                for (int tt = 0; tt < 8; ++tt) {
                    const int tf = tt + dt;
                    offt[tt * KMAX + j] =
                        (tf >= 0 && tf < 8) ? (unsigned int)lin : MARKER;
                }
            }
            ++j;
        }
    }
    for (int p = J + c; p < Kpad; p += 256) {
        idx[p] = 3u << 8;
        cval[p] = 0.f;
        #pragma unroll
        for (int tt = 0; tt < 8; ++tt) offt[tt * KMAX + p] = MARKER;
    }
}

// ---- pre-pass 2: A3 fragment-major: A3[(slot*256+o)*8+e], slot=kk*4+koct ----
__global__ __launch_bounds__(256)
void build_A3(const float* __restrict__ netw, const unsigned int* __restrict__ meta,
              const unsigned int* __restrict__ idx, const float* __restrict__ cval,
              unsigned short* __restrict__ A3)
{
    const int o = blockIdx.x;
    const int Kpad   = (int)meta[0];
    const int nslots = Kpad >> 3;
    for (int s = threadIdx.x; s < nslots; s += 256) {
        unsigned short v[8];
        #pragma unroll
        for (int e = 0; e < 8; ++e) {
            const int jj = s * 8 + e;
            const int c  = (int)(idx[jj] & 255u);
            v[e] = f2b(netw[o * C_TOT + c] * cval[jj]);
        }
        *reinterpret_cast<u32x4*>(&A3[((size_t)s * 256 + o) * 8]) =
            *reinterpret_cast<const u32x4*>(v);
    }
}

// ---- barrier-free gather GEMM, depth-2 software pipeline ----
// Block = one frame x one 64-px tile; wave = one 64-o group, fully independent.
// Per K-step kk: issue (kk+1)'s A-frags + B-gathers and (kk+2)'s offsets
// BEFORE kk's pack+MFMA. Full unroll -> all buffer indices compile-time.
__global__ __launch_bounds__(256, 2)
void msce_gather(const float* __restrict__ x,
                 const unsigned short* __restrict__ A3,
                 const unsigned int* __restrict__ offt,
                 const unsigned int* __restrict__ meta,
                 const float* __restrict__ net_b,
                 float* __restrict__ out)
{
    const int Kpad = (int)meta[0];
    const int KK   = Kpad >> 5;

    const int tid  = threadIdx.x;
    const int wave = tid >> 6;       // = o-group 0..3
    const int lane = tid & 63;

#if USE_RAW_BUF
    const __amdgpu_buffer_rsrc_t rsrc =
        __builtin_amdgcn_make_buffer_rsrc((void*)x, (short)0,
                                          (int)XBYTES, 0x00020000);
    #define GLOAD(ofs) __builtin_bit_cast(float, \
        __builtin_amdgcn_raw_buffer_load_b32(rsrc, (int)(ofs), 0, 0))
#else
    #define GLOAD(ofs) (((ofs) < (unsigned int)XBYTES) ? x[(ofs) >> 2] : 0.f)
#endif

    // bijective XCD swizzle: 1664 = 8 x 208 -> 16 consecutive frames per XCD
    const int bid  = blockIdx.x;
    const int work = (bid & 7) * 208 + (bid >> 3);
    const int n    = work / 13;
    const int tile = work - n * 13;
    const int p0   = (tile < 12) ? tile * 64 : 720;   // tile 12 overlaps 11 (benign)
    const int t    = n & 7;

    const int og   = wave;
    const int koct = lane >> 4;
    const int prow = lane & 15;
    const unsigned int n_off = (unsigned int)n * (unsigned int)(C_TOT * HW_ * 4);
    const unsigned int* offrow = offt + (size_t)t * KMAX;

    // pixel-column byte offsets (loop-invariant)
    unsigned int pofs[4];
    #pragma unroll
    for (int ns = 0; ns < 4; ++ns)
        pofs[ns] = n_off + (unsigned int)((p0 + ns * 16 + prow) * 4);

    // acc init = bias (D layout: col=prow, row = og*64 + ms*16 + koct*4 + r)
    f32x4 acc[4][4];
    #pragma unroll
    for (int ms = 0; ms < 4; ++ms) {
        const f32x4 b = *reinterpret_cast<const f32x4*>(
                            &net_b[og * 64 + ms * 16 + koct * 4]);
        #pragma unroll
        for (int ns = 0; ns < 4; ++ns) acc[ms][ns] = b;
    }

    auto load_off = [&](int kk, unsigned int (&o8)[8]) {
        #pragma unroll
        for (int e = 0; e < 8; ++e)
            o8[e] = offrow[kk * 32 + koct * 8 + e];
    };
    auto load_af = [&](int kk, short8 (&af)[4]) {
        const unsigned short* abase =
            A3 + ((size_t)(kk * 4 + koct) * 256 + og * 64 + prow) * 8;
        #pragma unroll
        for (int ms = 0; ms < 4; ++ms)
            af[ms] = *reinterpret_cast<const short8*>(abase + (size_t)ms * 16 * 8);
    };
    auto issue_g = [&](const unsigned int (&o8)[8], float (&g)[32]) {
        #pragma unroll
        for (int ns = 0; ns < 4; ++ns)
            #pragma unroll
            for (int e = 0; e < 8; ++e)
                g[ns * 8 + e] = GLOAD(o8[e] + pofs[ns]);
    };
    auto compute = [&](const short8 (&af)[4], const float (&g)[32]) {
        short8 bfr[4];
        #pragma unroll
        for (int ns = 0; ns < 4; ++ns) {
            u32x4 bw;
            bw[0] = pk2(g[ns * 8 + 0], g[ns * 8 + 1]);
            bw[1] = pk2(g[ns * 8 + 2], g[ns * 8 + 3]);
            bw[2] = pk2(g[ns * 8 + 4], g[ns * 8 + 5]);
            bw[3] = pk2(g[ns * 8 + 6], g[ns * 8 + 7]);
            bfr[ns] = __builtin_bit_cast(short8, bw);
        }
        #pragma unroll
        for (int ms = 0; ms < 4; ++ms)
            #pragma unroll
            for (int ns = 0; ns < 4; ++ns)
                acc[ms][ns] = __builtin_amdgcn_mfma_f32_16x16x32_bf16(
                                  af[ms], bfr[ns], acc[ms][ns], 0, 0, 0);
    };

    if (Kpad == KPAD_STD) {
        // depth-2 pipeline over 11 fully-unrolled steps (static buffer parity)
        unsigned int o8_[2][8];
        short8       af_[2][4];
        float        g_[2][32];

        load_off(0, o8_[0]);
        load_off(1, o8_[1]);
        load_af(0, af_[0]);
        issue_g(o8_[0], g_[0]);

        #pragma unroll
        for (int kk = 0; kk < 11; ++kk) {
            const int cur = kk & 1, nxt = (kk + 1) & 1;
            if (kk + 1 < 11) {
                load_af(kk + 1, af_[nxt]);
                issue_g(o8_[nxt], g_[nxt]);     // gathers in flight across MFMA
            }
            if (kk + 2 < 11)
                load_off(kk + 2, o8_[cur]);     // slot freed: g(kk) already issued
            compute(af_[cur], g_[cur]);
        }
    } else {          // generic fallback (unpipelined)
        for (int kk = 0; kk < KK; ++kk) {
            unsigned int o8[8];
            short8 af[4];
            float g[32];
            load_off(kk, o8);
            load_af(kk, af);
            issue_g(o8, g);
            compute(af, g);
        }
    }
    #undef GLOAD

    // ---- store: out[n][o][p], f32 ----
    #pragma unroll
    for (int ns = 0; ns < 4; ++ns) {
        const int p = p0 + ns * 16 + prow;
        #pragma unroll
        for (int ms = 0; ms < 4; ++ms) {
            const int o = og * 64 + ms * 16 + koct * 4;
            const size_t base = ((size_t)n * O_TOT + o) * HW_ + p;
            #pragma unroll
            for (int r = 0; r < 4; ++r)
                out[base + (size_t)r * HW_] = acc[ms][ns][r];
        }
    }
}

extern "C" void kernel_launch(void* const* d_in, const int* in_sizes, int n_in,
                              void* d_out, int out_size, void* d_ws, size_t ws_size,
                              hipStream_t stream) {
    const float* x    = (const float*)d_in[0];
    const float* w3p  = (const float*)d_in[1];
    const float* w5p  = (const float*)d_in[2];
    const float* w7p  = (const float*)d_in[3];
    const float* netw = (const float*)d_in[4];
    const float* netb = (const float*)d_in[5];
    float* outp = (float*)d_out;

    char* ws = (char*)d_ws;
    unsigned int*   meta = (unsigned int*)ws;
    unsigned int*   idx  = (unsigned int*)(ws + WS_IDX_OFF);
    float*          cval = (float*)(ws + WS_CVAL_OFF);
    unsigned int*   offt = (unsigned int*)(ws + WS_OFFT_OFF);
    unsigned short* A3   = (unsigned short*)(ws + WS_A3_OFF);

    hipLaunchKernelGGL(build_idx, dim3(1), dim3(256), 0, stream,
                       w3p, w5p, w7p, meta, idx, cval, offt);
    hipLaunchKernelGGL(build_A3, dim3(256), dim3(256), 0, stream,
                       netw, meta, idx, cval, A3);

    hipLaunchKernelGGL(msce_gather, dim3(1664), dim3(256), 0, stream,
                       x, A3, offt, meta, netb, outp);
}